// Round 2
// baseline (706.706 us; speedup 1.0000x reference)
//
#include <hip/hip_runtime.h>
#include <math.h>

#define NB    8192
#define EMB   512
#define POOL  100

// ---- fused-kernel geometry ----
#define BM    32      // rows per block
#define BN    256     // j-tile width (phase 1)
#define BK    64      // k-chunk (phase 1)
#define AS_STRIDE 36     // As[kk][r]  (k-major xq tile; 144B rows, 16B-aligned)
#define XT_STRIDE 516    // xt[r][j]   (ROW-major x tile; 2064B rows, 16B-aligned)
#define BS_STRIDE 260    // Bs[kk][j]  (1040B rows, 16B-aligned)
#define KS_STRIDE 104    // Ks[kk][key] (416B rows, 16B-aligned)
#define SC_STRIDE 101    // scores[r][j]

// ---------------- K0: inverse L2 norms of clip_key rows ----------------
__global__ __launch_bounds__(64) void key_norms_k(const float* __restrict__ K,
                                                  float* __restrict__ inv) {
    const int key  = blockIdx.x;
    const int lane = threadIdx.x;           // 64 lanes, wave64
    const float4* row = (const float4*)(K + (size_t)key * EMB);
    float4 v0 = row[lane];
    float4 v1 = row[lane + 64];
    float s = v0.x*v0.x + v0.y*v0.y + v0.z*v0.z + v0.w*v0.w
            + v1.x*v1.x + v1.y*v1.y + v1.z*v1.z + v1.w*v1.w;
    #pragma unroll
    for (int off = 32; off > 0; off >>= 1) s += __shfl_xor(s, off);
    if (lane == 0) inv[key] = 1.0f / fmaxf(sqrtf(s), 1e-12f);
}

// ------- K1: fused x=relu(xq@W^T+b) -> scores vs scaled keys -> top-4 -------
// 256 blocks x 512 threads; 32 rows/block.
// Phase 1 micro-tile: 4 rows x 4 cols per thread; rt = tid>>6 is WAVE-UNIFORM,
// so the A-fragment ds_read_b128 is same-address across the wave (broadcast).
__global__ __launch_bounds__(512) void fused_score_topk_k(
    const float* __restrict__ xq,    // [8192][512]
    const float* __restrict__ W,     // [512][512]
    const float* __restrict__ bias,  // [512]
    const float* __restrict__ Kc,    // [100][512]
    const float* __restrict__ inv,   // [100]
    int* __restrict__ idx_out)       // [8192][4]
{
    __shared__ float xt[BM * XT_STRIDE];    // 66048 B : x row-major
    __shared__ float As[BK * AS_STRIDE];    //  9216 B : xq tile, k-major
    __shared__ float ubuf[BK * BS_STRIDE];  // 66560 B : Bs / Ks / scores (reused)
    // total LDS = 141824 B -> 1 block/CU

    const int tid = threadIdx.x;
    const int r0  = blockIdx.x * BM;
    const int rt  = tid >> 6;     // 0..7  row-group == wave id
    const int ct  = tid & 63;     // 0..63 col-thread (lane)

    // ================= phase 1: x = relu(xq @ W^T + b) =================
    for (int jt = 0; jt < EMB; jt += BN) {
        float acc[4][4];
        #pragma unroll
        for (int i = 0; i < 4; ++i)
            #pragma unroll
            for (int q = 0; q < 4; ++q) acc[i][q] = 0.f;

        for (int kt = 0; kt < EMB; kt += BK) {
            // stage As[kk][r] = xq[r0+r][kt+kk]   (512 float4, 1/thread)
            {
                int r  = tid >> 4;             // 0..31
                int kq = (tid & 15) << 2;      // 0..60
                float4 v = *(const float4*)(xq + (size_t)(r0 + r) * EMB + kt + kq);
                As[(kq+0)*AS_STRIDE + r] = v.x;
                As[(kq+1)*AS_STRIDE + r] = v.y;
                As[(kq+2)*AS_STRIDE + r] = v.z;
                As[(kq+3)*AS_STRIDE + r] = v.w;
            }
            // stage Bs[kk][j] = W[jt+j][kt+kk]    (4096 float4, 8/thread)
            #pragma unroll
            for (int i = 0; i < 8; ++i) {
                int u  = tid + (i << 9);
                int j  = u >> 4;               // 0..255
                int kq = (u & 15) << 2;        // 0..60
                float4 v = *(const float4*)(W + (size_t)(jt + j) * EMB + kt + kq);
                ubuf[(kq+0)*BS_STRIDE + j] = v.x;
                ubuf[(kq+1)*BS_STRIDE + j] = v.y;
                ubuf[(kq+2)*BS_STRIDE + j] = v.z;
                ubuf[(kq+3)*BS_STRIDE + j] = v.w;
            }
            __syncthreads();
            #pragma unroll 16
            for (int kk = 0; kk < BK; ++kk) {
                float4 a = *(const float4*)&As[kk*AS_STRIDE + (rt<<2)];   // broadcast
                float4 b = *(const float4*)&ubuf[kk*BS_STRIDE + (ct<<2)]; // contiguous
                acc[0][0] += a.x*b.x; acc[0][1] += a.x*b.y; acc[0][2] += a.x*b.z; acc[0][3] += a.x*b.w;
                acc[1][0] += a.y*b.x; acc[1][1] += a.y*b.y; acc[1][2] += a.y*b.z; acc[1][3] += a.y*b.w;
                acc[2][0] += a.z*b.x; acc[2][1] += a.z*b.y; acc[2][2] += a.z*b.z; acc[2][3] += a.z*b.w;
                acc[3][0] += a.w*b.x; acc[3][1] += a.w*b.y; acc[3][2] += a.w*b.z; acc[3][3] += a.w*b.w;
            }
            __syncthreads();
        }
        // epilogue: bias + relu -> xt row-major, contiguous float4 stores
        {
            float4 bv = *(const float4*)(bias + jt + (ct<<2));
            #pragma unroll
            for (int i = 0; i < 4; ++i) {
                int r = (rt<<2) + i;
                float4 o;
                o.x = fmaxf(acc[i][0] + bv.x, 0.f);
                o.y = fmaxf(acc[i][1] + bv.y, 0.f);
                o.z = fmaxf(acc[i][2] + bv.z, 0.f);
                o.w = fmaxf(acc[i][3] + bv.w, 0.f);
                *(float4*)&xt[r*XT_STRIDE + jt + (ct<<2)] = o;
            }
        }
    }
    __syncthreads();   // xt complete, ubuf free

    // ================= phase 2: scores = x . (K*invnorm) =================
    // thread grid 16x32: 2 rows x 4 keys per thread; active keys: tc<25
    const int tr = tid >> 5;      // 0..15
    const int tc = tid & 31;      // 0..31
    float sacc[2][4] = {{0.f,0.f,0.f,0.f},{0.f,0.f,0.f,0.f}};
    for (int kt = 0; kt < EMB; kt += 32) {
        __syncthreads();   // previous consumers of ubuf done
        // stage Ks[kk][key] = Kc[key][kt+kk] * inv[key]   (800 float4)
        for (int u = tid; u < 800; u += 512) {
            int key = u >> 3;
            int kq  = (u & 7) << 2;
            float iv = inv[key];
            float4 v = *(const float4*)(Kc + (size_t)key * EMB + kt + kq);
            ubuf[(kq+0)*KS_STRIDE + key] = v.x * iv;
            ubuf[(kq+1)*KS_STRIDE + key] = v.y * iv;
            ubuf[(kq+2)*KS_STRIDE + key] = v.z * iv;
            ubuf[(kq+3)*KS_STRIDE + key] = v.w * iv;
        }
        __syncthreads();
        if (tc < 25) {
            #pragma unroll
            for (int kk = 0; kk < 32; ++kk) {
                float a0 = xt[(tr<<1)*XT_STRIDE + kt + kk];        // broadcast
                float a1 = xt[((tr<<1)+1)*XT_STRIDE + kt + kk];    // broadcast
                float4 b = *(const float4*)&ubuf[kk*KS_STRIDE + (tc<<2)];
                sacc[0][0] += a0*b.x; sacc[0][1] += a0*b.y; sacc[0][2] += a0*b.z; sacc[0][3] += a0*b.w;
                sacc[1][0] += a1*b.x; sacc[1][1] += a1*b.y; sacc[1][2] += a1*b.z; sacc[1][3] += a1*b.w;
            }
        }
    }

    // ================= phase 3: top-4 per row =================
    __syncthreads();   // done reading ubuf as Ks
    if (tc < 25) {
        #pragma unroll
        for (int i = 0; i < 2; ++i)
            #pragma unroll
            for (int q = 0; q < 4; ++q)
                ubuf[((tr<<1)+i)*SC_STRIDE + (tc<<2) + q] = sacc[i][q];
    }
    __syncthreads();
    if (tid < BM) {
        const float* srow = &ubuf[tid * SC_STRIDE];
        float v0=-INFINITY, v1=-INFINITY, v2=-INFINITY, v3=-INFINITY;
        int   i0=0, i1=0, i2=0, i3=0;
        for (int j = 0; j < POOL; ++j) {
            float s = srow[j];
            if (s > v3) {       // strict > : stable ties like jax top_k
                if (s > v0)      { v3=v2;i3=i2; v2=v1;i2=i1; v1=v0;i1=i0; v0=s;i0=j; }
                else if (s > v1) { v3=v2;i3=i2; v2=v1;i2=i1; v1=s;i1=j; }
                else if (s > v2) { v3=v2;i3=i2; v2=s;i2=j; }
                else             { v3=s;i3=j; }
            }
        }
        int4 w; w.x=i0; w.y=i1; w.z=i2; w.w=i3;
        *(int4*)(idx_out + (size_t)(r0 + tid) * 4) = w;
    }
}

// ---------------- K2: gather Ck/Cv + passthrough x_block ----------------
// out layout: Ck [8192][16][512] | Cv [8192][16][512] | x_block [8192][512]
__global__ __launch_bounds__(256) void gather_k(
    const float* __restrict__ c_pool,   // [100][8][512]
    const float* __restrict__ x_block,  // [8192][512]
    const int*   __restrict__ idx,      // [8192][4]
    float* __restrict__ out)
{
    const int b   = blockIdx.x;
    const int tid = threadIdx.x;
    const int F4  = EMB / 4;   // 128 float4 per row

    int4 id = *(const int4*)(idx + (size_t)b * 4);

    float4*       outCk = (float4*)out + (size_t)b * 16 * F4;
    float4*       outCv = (float4*)out + (size_t)NB * 16 * F4 + (size_t)b * 16 * F4;
    float4*       outX  = (float4*)out + (size_t)2 * NB * 16 * F4 + (size_t)b * F4;
    const float4* cp    = (const float4*)c_pool;
    const float4* xb    = (const float4*)x_block + (size_t)b * F4;

    #pragma unroll
    for (int t = 0; t < 4; ++t) {
        int id_t = (t == 0) ? id.x : (t == 1) ? id.y : (t == 2) ? id.z : id.w;
        const float4* src = cp + (size_t)(id_t * 8) * F4;   // 8 ctx rows of this pool entry
        #pragma unroll
        for (int i = 0; i < 2; ++i) {          // 512 float4 per t-slot / 256 thr
            int u = tid + (i << 8);
            int c = u >> 7;                    // 0..3
            int j = u & 127;
            outCk[(t*4 + c) * F4 + j] = src[c * F4 + j];          // half 0..3
            outCv[(t*4 + c) * F4 + j] = src[(4 + c) * F4 + j];    // half 4..7
        }
    }
    if (tid < F4) outX[tid] = xb[tid];
}

extern "C" void kernel_launch(void* const* d_in, const int* in_sizes, int n_in,
                              void* d_out, int out_size, void* d_ws, size_t ws_size,
                              hipStream_t stream) {
    (void)in_sizes; (void)n_in; (void)out_size; (void)ws_size;
    const float* x_block  = (const float*)d_in[0];
    const float* x_query  = (const float*)d_in[1];   // [8192][1][512] == [8192][512]
    const float* clip_key = (const float*)d_in[2];
    const float* W        = (const float*)d_in[3];
    const float* bias     = (const float*)d_in[4];
    const float* c_pool   = (const float*)d_in[5];
    // d_in[6] = l : unused by the reference

    float* inv = (float*)d_ws;                       // 100 floats
    int*   idx = (int*)((char*)d_ws + 512);          // 8192*4 ints (16B-aligned)
    float* out = (float*)d_out;

    key_norms_k<<<POOL, 64, 0, stream>>>(clip_key, inv);
    fused_score_topk_k<<<NB / BM, 512, 0, stream>>>(x_query, W, bias, clip_key, inv, idx);
    gather_k<<<NB, 256, 0, stream>>>(c_pool, x_block, idx, out);
}

// Round 6
// 698.148 us; speedup vs baseline: 1.0123x; 1.0123x over previous
//
#include <hip/hip_runtime.h>
#include <math.h>

#define NB    8192
#define EMB   512
#define POOL  100

// fused-kernel geometry: 512 blocks x 256 threads, 16 rows/block, 2 blocks/CU
#define BM    16
#define BN    256     // j-tile (2 jt passes)
#define BK    32      // k-chunk
#define AS_S  36      // As[r][k]  row-major, stride 36 words = 9*16B (odd 16B mult)
#define BS_S  36      // Bs[j][k]  row-major, stride 36 words
#define XT_S  516     // xt[r][j]  row-major
#define KS_S  100     // Ks[kk][key] k-major
#define SC_S  101     // scores[r][j]

typedef float v4f __attribute__((ext_vector_type(4)));   // NT-store-compatible

// ---------------- K0: inverse L2 norms of clip_key rows ----------------
__global__ __launch_bounds__(64) void key_norms_k(const float* __restrict__ K,
                                                  float* __restrict__ inv) {
    const int key  = blockIdx.x;
    const int lane = threadIdx.x;
    const float4* row = (const float4*)(K + (size_t)key * EMB);
    float4 v0 = row[lane];
    float4 v1 = row[lane + 64];
    float s = v0.x*v0.x + v0.y*v0.y + v0.z*v0.z + v0.w*v0.w
            + v1.x*v1.x + v1.y*v1.y + v1.z*v1.z + v1.w*v1.w;
    #pragma unroll
    for (int off = 32; off > 0; off >>= 1) s += __shfl_xor(s, off);
    if (lane == 0) inv[key] = 1.0f / fmaxf(sqrtf(s), 1e-12f);
}

// ---- fused: GEMM(16 rows) -> scores -> top4 -> gather, all in one block ----
__global__ __launch_bounds__(256, 2) void fused_all_k(
    const float* __restrict__ xq,       // [8192][512]
    const float* __restrict__ W,        // [512][512]
    const float* __restrict__ bias,     // [512]
    const float* __restrict__ Kc,       // [100][512]
    const float* __restrict__ inv,      // [100]
    const float* __restrict__ c_pool,   // [100][8][512]
    const float* __restrict__ x_block,  // [8192][512]
    float* __restrict__ out)
{
    __shared__ float As[BM * AS_S];      //  2304 B
    __shared__ float Bs[BN * BS_S];      // 36864 B (reused: Ks, scores)
    __shared__ float xt[BM * XT_S];      // 33024 B
    __shared__ int4  sIdx[BM];           //   256 B   -> total 72448 B, 2 blk/CU

    const int tid = threadIdx.x;
    const int r0  = blockIdx.x * BM;

    // ================= phase 1: x = relu(xq @ W^T + b) =================
    // 4 row-groups (rt = tid>>6, wave-uniform) x 64 col-threads.
    // Per-thread 4x4 tile; cols strided by 64 so row->bank-group covers all 8.
    const int rt = tid >> 6;     // 0..3
    const int ct = tid & 63;     // 0..63

    for (int jt = 0; jt < EMB; jt += BN) {
        float acc[4][4];
        #pragma unroll
        for (int i = 0; i < 4; ++i)
            #pragma unroll
            for (int q = 0; q < 4; ++q) acc[i][q] = 0.f;

        for (int kt = 0; kt < EMB; kt += BK) {
            __syncthreads();   // previous round's readers done
            // stage As[r][kq] (128 float4, b128 stores at BW floor)
            if (tid < 128) {
                int r  = tid >> 3;
                int kq = (tid & 7) << 2;
                float4 v = *(const float4*)(xq + (size_t)(r0 + r) * EMB + kt + kq);
                *(float4*)&As[r * AS_S + kq] = v;
            }
            // stage Bs[j][kq] (2048 float4, 8/thread, b128 stores, no transpose)
            #pragma unroll
            for (int i = 0; i < 8; ++i) {
                int u  = tid + (i << 8);
                int j  = u >> 3;               // 0..255
                int kq = (u & 7) << 2;         // 0..28
                float4 v = *(const float4*)(W + (size_t)(jt + j) * EMB + kt + kq);
                *(float4*)&Bs[j * BS_S + kq] = v;
            }
            __syncthreads();
            // compute: per 4-kk step: 4 broadcast A b128 + 4 B b128 + 64 FMA
            #pragma unroll
            for (int kk = 0; kk < BK; kk += 4) {
                float4 a[4], b[4];
                #pragma unroll
                for (int i = 0; i < 4; ++i)
                    a[i] = *(const float4*)&As[((rt << 2) + i) * AS_S + kk];  // broadcast
                #pragma unroll
                for (int q = 0; q < 4; ++q)
                    b[q] = *(const float4*)&Bs[(ct + (q << 6)) * BS_S + kk];
                #pragma unroll
                for (int i = 0; i < 4; ++i)
                    #pragma unroll
                    for (int q = 0; q < 4; ++q)
                        acc[i][q] += a[i].x*b[q].x + a[i].y*b[q].y
                                   + a[i].z*b[q].z + a[i].w*b[q].w;
            }
        }
        // epilogue: bias + relu -> xt row-major (b32 stores, wave-contiguous)
        #pragma unroll
        for (int q = 0; q < 4; ++q) {
            float bq = bias[jt + ct + (q << 6)];
            #pragma unroll
            for (int i = 0; i < 4; ++i)
                xt[((rt << 2) + i) * XT_S + jt + ct + (q << 6)]
                    = fmaxf(acc[i][q] + bq, 0.f);
        }
    }

    // ================= phase 2: scores = x . (K*invnorm) =================
    // 8 row-pairs (tr) x 32 key-threads (tc<25 active, 4 keys each)
    const int tr = tid >> 5;     // 0..7 -> rows 2tr, 2tr+1
    const int tc = tid & 31;
    float* Ks = Bs;              // [32][100] k-major, reuse
    float sacc[2][4] = {{0.f,0.f,0.f,0.f},{0.f,0.f,0.f,0.f}};
    for (int kt = 0; kt < EMB; kt += 32) {
        __syncthreads();         // previous Ks readers (or phase-1 Bs) done
        for (int u = tid; u < 800; u += 256) {
            int key = u >> 3;
            int kq  = (u & 7) << 2;
            float iv = inv[key];
            float4 v = *(const float4*)(Kc + (size_t)key * EMB + kt + kq);
            Ks[(kq+0)*KS_S + key] = v.x * iv;
            Ks[(kq+1)*KS_S + key] = v.y * iv;
            Ks[(kq+2)*KS_S + key] = v.z * iv;
            Ks[(kq+3)*KS_S + key] = v.w * iv;
        }
        __syncthreads();
        if (tc < 25) {
            #pragma unroll
            for (int kk = 0; kk < 32; ++kk) {
                float a0 = xt[(tr << 1) * XT_S + kt + kk];         // broadcast
                float a1 = xt[((tr << 1) + 1) * XT_S + kt + kk];   // broadcast
                float4 b = *(const float4*)&Ks[kk * KS_S + (tc << 2)];
                sacc[0][0] += a0*b.x; sacc[0][1] += a0*b.y;
                sacc[0][2] += a0*b.z; sacc[0][3] += a0*b.w;
                sacc[1][0] += a1*b.x; sacc[1][1] += a1*b.y;
                sacc[1][2] += a1*b.z; sacc[1][3] += a1*b.w;
            }
        }
    }

    // ================= phase 3: top-4 per row =================
    __syncthreads();
    float* sc = Bs;              // [16][101], reuse
    if (tc < 25) {
        #pragma unroll
        for (int i = 0; i < 2; ++i)
            #pragma unroll
            for (int q = 0; q < 4; ++q)
                sc[((tr << 1) + i) * SC_S + (tc << 2) + q] = sacc[i][q];
    }
    __syncthreads();
    if (tid < BM) {
        const float* srow = &sc[tid * SC_S];
        float v0=-INFINITY, v1=-INFINITY, v2=-INFINITY, v3=-INFINITY;
        int   i0=0, i1=0, i2=0, i3=0;
        for (int j = 0; j < POOL; ++j) {
            float s = srow[j];
            if (s > v3) {        // strict > : first index wins ties (jax top_k)
                if (s > v0)      { v3=v2;i3=i2; v2=v1;i2=i1; v1=v0;i1=i0; v0=s;i0=j; }
                else if (s > v1) { v3=v2;i3=i2; v2=v1;i2=i1; v1=s;i1=j; }
                else if (s > v2) { v3=v2;i3=i2; v2=s;i2=j; }
                else             { v3=s;i3=j; }
            }
        }
        int4 w; w.x=i0; w.y=i1; w.z=i2; w.w=i3;
        sIdx[tid] = w;
    }
    __syncthreads();

    // ================= phase 4: gather (NT stores; keep c_pool in L2) ======
    // out layout: Ck [8192][16][512] | Cv [8192][16][512] | x [8192][512]
    float4*       out4 = (float4*)out;
    const float4* cp4  = (const float4*)c_pool;
    const float4* xb4  = (const float4*)x_block;
    const size_t  CV0  = (size_t)NB * 2048;
    const size_t  X0   = (size_t)2 * NB * 2048;

    for (int r = 0; r < BM; ++r) {
        int4 id = sIdx[r];                       // LDS broadcast
        int ids[4] = {id.x, id.y, id.z, id.w};
        float4* oCk = out4 + (size_t)(r0 + r) * 2048;
        float4* oCv = out4 + CV0 + (size_t)(r0 + r) * 2048;
        #pragma unroll
        for (int t = 0; t < 4; ++t) {
            const float4* src = cp4 + (size_t)ids[t] * 1024;   // [8][128] f4
            #pragma unroll
            for (int rep = 0; rep < 2; ++rep) {
                int u = tid + (rep << 8);
                int c = u >> 7;                  // 0..3
                int j = u & 127;
                __builtin_nontemporal_store(*(const v4f*)&src[c * 128 + j],
                                            (v4f*)&oCk[((t << 2) + c) * 128 + j]);
                __builtin_nontemporal_store(*(const v4f*)&src[(c + 4) * 128 + j],
                                            (v4f*)&oCv[((t << 2) + c) * 128 + j]);
            }
        }
    }
    // x_block passthrough: 16 rows x 128 float4 = 8/thread
    #pragma unroll
    for (int rep = 0; rep < 8; ++rep) {
        int u = tid + (rep << 8);
        int r = u >> 7;
        int j = u & 127;
        __builtin_nontemporal_store(*(const v4f*)&xb4[(size_t)(r0 + r) * 128 + j],
                                    (v4f*)&out4[X0 + (size_t)(r0 + r) * 128 + j]);
    }
}

extern "C" void kernel_launch(void* const* d_in, const int* in_sizes, int n_in,
                              void* d_out, int out_size, void* d_ws, size_t ws_size,
                              hipStream_t stream) {
    (void)in_sizes; (void)n_in; (void)out_size; (void)ws_size;
    const float* x_block  = (const float*)d_in[0];
    const float* x_query  = (const float*)d_in[1];
    const float* clip_key = (const float*)d_in[2];
    const float* W        = (const float*)d_in[3];
    const float* bias     = (const float*)d_in[4];
    const float* c_pool   = (const float*)d_in[5];
    // d_in[6] = l : unused by the reference

    float* inv = (float*)d_ws;   // 100 floats
    float* out = (float*)d_out;

    key_norms_k<<<POOL, 64, 0, stream>>>(clip_key, inv);
    fused_all_k<<<NB / BM, 256, 0, stream>>>(x_query, W, bias, clip_key, inv,
                                             c_pool, x_block, out);
}